// Round 1
// baseline (164.610 us; speedup 1.0000x reference)
//
#include <hip/hip_runtime.h>

static constexpr int NN = 4194304;   // N
// ALPHA = 0.7 applied in finalize kernel

// ---------------------------------------------------------------------------
// Main reduction kernel: grid-stride over groups of 4 rows, float4-vectorized.
// Accumulates three partial sums:
//   acc[0] = sum (pred_prices - tgt_prices)^2
//   acc[1] = sum CE_i  (logsumexp(logits) - logits[tgt])
//   acc[2] = sum sigmoid(10 * profit_i)
// ---------------------------------------------------------------------------
__global__ __launch_bounds__(256) void pfl_main(
    const float* __restrict__ pp,   // pred_prices [N]
    const float* __restrict__ pa,   // pred_actions [N,3]
    const float* __restrict__ tp,   // tgt_prices [N]
    const int*   __restrict__ ta,   // tgt_actions [N] (int32)
    double* __restrict__ acc)
{
    const int G = NN / 4;           // 1048576 groups of 4 rows
    float sq = 0.f, ce = 0.f, pw = 0.f;

    const float4* pp4 = (const float4*)pp;
    const float4* tp4 = (const float4*)tp;
    const float4* pa4 = (const float4*)pa;
    const int4*   ta4 = (const int4*)ta;

    for (int g = blockIdx.x * blockDim.x + threadIdx.x; g < G;
         g += gridDim.x * blockDim.x) {
        const int i = g * 4;
        float4 p  = pp4[g];
        float4 t  = tp4[g];
        int4   a  = ta4[g];
        float4 A0 = pa4[3*g + 0];
        float4 A1 = pa4[3*g + 1];
        float4 A2 = pa4[3*g + 2];

        // neighbor tgt_prices (L1-cached re-reads); guarded uses below
        float tm1  = (i > 0)      ? tp[i - 1] : 0.f;
        float tnx  = (i + 4 < NN) ? tp[i + 4] : 0.f;

        float tv[6]     = {tm1, t.x, t.y, t.z, t.w, tnx};
        float pv[4]     = {p.x, p.y, p.z, p.w};
        float rows[4][3] = {{A0.x, A0.y, A0.z},
                            {A0.w, A1.x, A1.y},
                            {A1.z, A1.w, A2.x},
                            {A2.y, A2.z, A2.w}};
        int av[4] = {a.x, a.y, a.z, a.w};

        #pragma unroll
        for (int j = 0; j < 4; ++j) {
            const int idx = i + j;
            // MSE term
            float d = pv[j] - tv[j + 1];
            sq += d * d;

            // cross-entropy via logsumexp (3 logits)
            float x0 = rows[j][0], x1 = rows[j][1], x2 = rows[j][2];
            float m  = fmaxf(x0, fmaxf(x1, x2));
            float lse = m + __logf(__expf(x0 - m) + __expf(x1 - m) + __expf(x2 - m));
            float tgt = (av[j] == 0) ? x0 : ((av[j] == 1) ? x1 : x2);
            ce += lse - tgt;

            // argmax (first-max semantics, matches jnp.argmax)
            int   pidx = 0;
            float best = x0;
            if (x1 > best) { best = x1; pidx = 1; }
            if (x2 > best) { pidx = 2; }

            float profit = 0.f;
            if (pidx == 0)      profit = (idx + 1 < NN) ? (tv[j + 2] - tv[j + 1]) : 0.f;
            else if (pidx == 2) profit = (idx > 0)      ? (tv[j + 1] - tv[j])     : 0.f;

            pw += 1.f / (1.f + __expf(-10.f * profit));
        }
    }

    // wave-64 shuffle reduction
    #pragma unroll
    for (int off = 32; off > 0; off >>= 1) {
        sq += __shfl_down(sq, off, 64);
        ce += __shfl_down(ce, off, 64);
        pw += __shfl_down(pw, off, 64);
    }

    __shared__ float s_sq[4], s_ce[4], s_pw[4];
    const int lane = threadIdx.x & 63;
    const int wid  = threadIdx.x >> 6;
    if (lane == 0) { s_sq[wid] = sq; s_ce[wid] = ce; s_pw[wid] = pw; }
    __syncthreads();

    if (threadIdx.x == 0) {
        float tsq = s_sq[0] + s_sq[1] + s_sq[2] + s_sq[3];
        float tce = s_ce[0] + s_ce[1] + s_ce[2] + s_ce[3];
        float tpw = s_pw[0] + s_pw[1] + s_pw[2] + s_pw[3];
        atomicAdd(&acc[0], (double)tsq);
        atomicAdd(&acc[1], (double)tce);
        atomicAdd(&acc[2], (double)tpw);
    }
}

// ---------------------------------------------------------------------------
// Finalize: combine the three sums into the scalar loss.
// out = 0.7 * (ce/N) * (pw/N) + 0.3 * (sq/N)
// ---------------------------------------------------------------------------
__global__ void pfl_final(const double* __restrict__ acc, float* __restrict__ out) {
    const double inv = 1.0 / (double)NN;
    double price_loss  = acc[0] * inv;
    double action_loss = acc[1] * inv;
    double mean_pw     = acc[2] * inv;
    out[0] = (float)(0.7 * action_loss * mean_pw + 0.3 * price_loss);
}

extern "C" void kernel_launch(void* const* d_in, const int* in_sizes, int n_in,
                              void* d_out, int out_size, void* d_ws, size_t ws_size,
                              hipStream_t stream) {
    const float* pp = (const float*)d_in[0];   // pred_prices
    const float* pa = (const float*)d_in[1];   // pred_actions [N,3]
    const float* tp = (const float*)d_in[2];   // tgt_prices
    const int*   ta = (const int*)d_in[3];     // tgt_actions (int32 per harness)
    // d_in[4] (prices) is unused by the reference — do not read it.

    double* acc = (double*)d_ws;
    hipMemsetAsync(acc, 0, 3 * sizeof(double), stream);  // ws is poisoned 0xAA

    pfl_main<<<1024, 256, 0, stream>>>(pp, pa, tp, ta, acc);
    pfl_final<<<1, 1, 0, stream>>>(acc, (float*)d_out);
}

// Round 2
// 136.181 us; speedup vs baseline: 1.2088x; 1.2088x over previous
//
#include <hip/hip_runtime.h>

static constexpr int NN  = 4194304;   // N
static constexpr int NB  = 2048;      // blocks
static constexpr int TPB = 256;       // threads per block
static constexpr int GPT = 2;         // groups of 4 rows per thread; NB*TPB*GPT*4 == NN

// ---------------------------------------------------------------------------
// Main reduction: each thread handles GPT groups of 4 rows, all loads hoisted
// ahead of compute for memory-level parallelism. Per-block partials go to
// distinct d_ws slots — NO global atomics (R1 theory: same-line double atomics
// across XCDs serialized the tail and dominated the 61 µs).
// ---------------------------------------------------------------------------
__global__ __launch_bounds__(256) void pfl_main(
    const float* __restrict__ pp,   // pred_prices [N]
    const float* __restrict__ pa,   // pred_actions [N,3]
    const float* __restrict__ tp,   // tgt_prices [N]
    const int*   __restrict__ ta,   // tgt_actions [N] (int32)
    float* __restrict__ bsum)       // [3*NB] per-block partials
{
    const int tid  = threadIdx.x;
    const int bid  = blockIdx.x;
    const int base = bid * (TPB * GPT);   // first group of this block

    const float4* pp4 = (const float4*)pp;
    const float4* tp4 = (const float4*)tp;
    const float4* pa4 = (const float4*)pa;
    const int4*   ta4 = (const int4*)ta;

    // ---- load phase: issue everything, then compute --------------------
    float4 p[GPT], t[GPT], A0[GPT], A1[GPT], A2[GPT];
    int4   a[GPT];
    float  tm1[GPT], tnx[GPT];

    #pragma unroll
    for (int k = 0; k < GPT; ++k) {
        const int g = base + k * TPB + tid;
        const int i = g * 4;
        p[k]  = pp4[g];
        t[k]  = tp4[g];
        a[k]  = ta4[g];
        A0[k] = pa4[3*g + 0];
        A1[k] = pa4[3*g + 1];
        A2[k] = pa4[3*g + 2];
        tm1[k] = (i > 0)      ? tp[i - 1] : 0.f;   // L1 hits (same lines as tp4)
        tnx[k] = (i + 4 < NN) ? tp[i + 4] : 0.f;
    }

    float sq = 0.f, ce = 0.f, pw = 0.f;

    #pragma unroll
    for (int k = 0; k < GPT; ++k) {
        const int g = base + k * TPB + tid;
        const int i = g * 4;
        float tv[6] = {tm1[k], t[k].x, t[k].y, t[k].z, t[k].w, tnx[k]};
        float pv[4] = {p[k].x, p[k].y, p[k].z, p[k].w};
        float rows[4][3] = {{A0[k].x, A0[k].y, A0[k].z},
                            {A0[k].w, A1[k].x, A1[k].y},
                            {A1[k].z, A1[k].w, A2[k].x},
                            {A2[k].y, A2[k].z, A2[k].w}};
        int av[4] = {a[k].x, a[k].y, a[k].z, a[k].w};

        #pragma unroll
        for (int j = 0; j < 4; ++j) {
            const int idx = i + j;
            // MSE
            float d = pv[j] - tv[j + 1];
            sq += d * d;

            // cross-entropy via logsumexp over 3 logits
            float x0 = rows[j][0], x1 = rows[j][1], x2 = rows[j][2];
            float m  = fmaxf(x0, fmaxf(x1, x2));
            float lse = m + __logf(__expf(x0 - m) + __expf(x1 - m) + __expf(x2 - m));
            float tgt = (av[j] == 0) ? x0 : ((av[j] == 1) ? x1 : x2);
            ce += lse - tgt;

            // argmax (first-max, matches jnp.argmax)
            int pidx = 0;
            float best = x0;
            if (x1 > best) { best = x1; pidx = 1; }
            if (x2 > best) { pidx = 2; }

            float profit = 0.f;
            if (pidx == 0)      profit = (idx + 1 < NN) ? (tv[j + 2] - tv[j + 1]) : 0.f;
            else if (pidx == 2) profit = (idx > 0)      ? (tv[j + 1] - tv[j])     : 0.f;

            pw += 1.f / (1.f + __expf(-10.f * profit));
        }
    }

    // ---- block reduction (wave-64 shuffle → LDS) -----------------------
    #pragma unroll
    for (int off = 32; off > 0; off >>= 1) {
        sq += __shfl_down(sq, off, 64);
        ce += __shfl_down(ce, off, 64);
        pw += __shfl_down(pw, off, 64);
    }

    __shared__ float s_sq[4], s_ce[4], s_pw[4];
    const int lane = tid & 63;
    const int wid  = tid >> 6;
    if (lane == 0) { s_sq[wid] = sq; s_ce[wid] = ce; s_pw[wid] = pw; }
    __syncthreads();

    if (tid == 0) {
        bsum[bid]          = s_sq[0] + s_sq[1] + s_sq[2] + s_sq[3];
        bsum[NB + bid]     = s_ce[0] + s_ce[1] + s_ce[2] + s_ce[3];
        bsum[2 * NB + bid] = s_pw[0] + s_pw[1] + s_pw[2] + s_pw[3];
    }
}

// ---------------------------------------------------------------------------
// Finalize: reduce NB per-block partials (double accumulation) and combine.
// out = 0.7 * (ce/N) * (pw/N) + 0.3 * (sq/N)
// ---------------------------------------------------------------------------
__global__ __launch_bounds__(256) void pfl_final(const float* __restrict__ bsum,
                                                 float* __restrict__ out) {
    double sq = 0.0, ce = 0.0, pw = 0.0;
    for (int i = threadIdx.x; i < NB; i += 256) {
        sq += (double)bsum[i];
        ce += (double)bsum[NB + i];
        pw += (double)bsum[2 * NB + i];
    }
    #pragma unroll
    for (int off = 32; off > 0; off >>= 1) {
        sq += __shfl_down(sq, off, 64);
        ce += __shfl_down(ce, off, 64);
        pw += __shfl_down(pw, off, 64);
    }
    __shared__ double s_sq[4], s_ce[4], s_pw[4];
    const int lane = threadIdx.x & 63;
    const int wid  = threadIdx.x >> 6;
    if (lane == 0) { s_sq[wid] = sq; s_ce[wid] = ce; s_pw[wid] = pw; }
    __syncthreads();

    if (threadIdx.x == 0) {
        double tsq = s_sq[0] + s_sq[1] + s_sq[2] + s_sq[3];
        double tce = s_ce[0] + s_ce[1] + s_ce[2] + s_ce[3];
        double tpw = s_pw[0] + s_pw[1] + s_pw[2] + s_pw[3];
        const double inv = 1.0 / (double)NN;
        out[0] = (float)(0.7 * (tce * inv) * (tpw * inv) + 0.3 * (tsq * inv));
    }
}

extern "C" void kernel_launch(void* const* d_in, const int* in_sizes, int n_in,
                              void* d_out, int out_size, void* d_ws, size_t ws_size,
                              hipStream_t stream) {
    const float* pp = (const float*)d_in[0];   // pred_prices
    const float* pa = (const float*)d_in[1];   // pred_actions [N,3]
    const float* tp = (const float*)d_in[2];   // tgt_prices
    const int*   ta = (const int*)d_in[3];     // tgt_actions (int32)
    // d_in[4] (prices) unused by reference.

    float* bsum = (float*)d_ws;                // 3*NB floats = 24 KB, written not accumulated

    pfl_main<<<NB, TPB, 0, stream>>>(pp, pa, tp, ta, bsum);
    pfl_final<<<1, TPB, 0, stream>>>(bsum, (float*)d_out);
}